// Round 14
// baseline (2053.088 us; speedup 1.0000x reference)
//
#include <hip/hip_runtime.h>
#include <hip/hip_bf16.h>

#define SEQ   2048
#define Dm    256
#define NE    1024
#define TT    16384   // B*S = 8*2048
#define TAU   0.05f   // (unused by k_vq now; kept for reference)
#define TAUQ  0.8f    // near-tie gap threshold for hi-only ranking (~8 sigma)
#define FLAGCAP 131072

typedef __attribute__((ext_vector_type(8))) short          bf16x8;
typedef __attribute__((ext_vector_type(4))) float          f32x4;
typedef __attribute__((ext_vector_type(8))) unsigned short us8;

__device__ __forceinline__ void bfsplit(float x, unsigned short& h, unsigned short& l){
    __hip_bfloat16 bh = __float2bfloat16(x);
    h = *reinterpret_cast<unsigned short*>(&bh);
    union { unsigned u; float f; } c; c.u = (unsigned)h << 16;
    __hip_bfloat16 bl = __float2bfloat16(x - c.f);
    l = *reinterpret_cast<unsigned short*>(&bl);
}

// ---------------------------------------------------------------- transpose
__global__ void k_transpose(const float* __restrict__ emb, float* __restrict__ embT){
    __shared__ float tile[32][33];
    const int n  = blockIdx.z;
    const int e0 = blockIdx.x << 5, d0 = blockIdx.y << 5;
    const int tx = threadIdx.x, ty = threadIdx.y;
    const float* src = emb + (size_t)n * Dm * NE;
    float* dst = embT + (size_t)n * NE * Dm;
    #pragma unroll
    for (int i = ty; i < 32; i += 8)
        tile[i][tx] = src[(size_t)(d0 + i) * NE + e0 + tx];
    __syncthreads();
    #pragma unroll
    for (int i = ty; i < 32; i += 8)
        dst[(size_t)(e0 + i) * Dm + d0 + tx] = tile[tx][i];
}

// ---------------------------------------------------------------- e2 norms (+ zero flag counter)
__global__ void k_e2(const float* __restrict__ emb, float* __restrict__ e2,
                     int* __restrict__ cnt){
    if (blockIdx.x == 0 && blockIdx.y == 0 && threadIdx.x == 0) *cnt = 0;
    const int n = blockIdx.y;
    const int e = (blockIdx.x << 8) + threadIdx.x;
    const float* p = emb + (size_t)n * Dm * NE + e;
    float s = 0.f;
    #pragma unroll 8
    for (int d = 0; d < Dm; ++d){ float v = p[(size_t)d * NE]; s = fmaf(v, v, s); }
    e2[n * NE + e] = s;
}

// ---------------------------------------------------------------- split embT into bf16 hi/lo
__global__ __launch_bounds__(256) void k_cvt(const float* __restrict__ embT,
                                             unsigned short* __restrict__ eh,
                                             unsigned short* __restrict__ el){
    const int i = ((blockIdx.x << 8) + threadIdx.x) << 2;
    const float4 v = *reinterpret_cast<const float4*>(&embT[i]);
    ushort4 h, l;
    bfsplit(v.x, h.x, l.x); bfsplit(v.y, h.y, l.y);
    bfsplit(v.z, h.z, l.z); bfsplit(v.w, h.w, l.w);
    *reinterpret_cast<ushort4*>(&eh[i]) = h;
    *reinterpret_cast<ushort4*>(&el[i]) = l;
}

// ---------------------------------------------------------------- prep banded conv weights
__global__ __launch_bounds__(256) void k_prep(
    const float* __restrict__ w0, const float* __restrict__ w1,
    const float* __restrict__ w2, const float* __restrict__ w3,
    unsigned short* __restrict__ bth, unsigned short* __restrict__ btl)
{
    const int dh = blockIdx.x;            // 0..6
    const int n  = blockIdx.y;            // 0..3
    const int kk = 2 * n + 1;
    if (dh >= kk) return;
    const float* wr[4] = { w0, w1, w2, w3 };
    const float* wp = wr[n] + dh * Dm;
    const int d = threadIdx.x;
    const size_t base = ((size_t)((n * 7 + dh) * 256 + d)) << 8;
    for (int mc = 0; mc < 256; mc += 4){
        ushort4 h, l;
        #pragma unroll
        for (int q = 0; q < 4; ++q){
            const int j = mc + q - d + 127;
            const float v = ((unsigned)j < 256u) ? wp[j] : 0.f;
            unsigned short hh, ll;
            bfsplit(v, hh, ll);
            (&h.x)[q] = hh; (&l.x)[q] = ll;
        }
        *reinterpret_cast<ushort4*>(&bth[base + mc]) = h;
        *reinterpret_cast<ushort4*>(&btl[base + mc]) = l;
    }
}

// ---------------------------------------------------------------- conv via split-bf16 MFMA
// Codebook-major. Emits f32 ic and pre-split bf16-hi (ich) for k_vq.
__global__ __launch_bounds__(256, 2) void k_conv(
    const float* __restrict__ x,
    const unsigned short* __restrict__ bth, const unsigned short* __restrict__ btl,
    const float* __restrict__ b0, const float* __restrict__ b1,
    const float* __restrict__ b2, const float* __restrict__ b3,
    float* __restrict__ ic, unsigned short* __restrict__ ich)
{
    __shared__ alignas(16) unsigned short Ahs[70][264];
    __shared__ alignas(16) unsigned short Als[70][264];

    const int tid  = threadIdx.x;
    const int lane = tid & 63;
    const int w    = tid >> 6;
    const int tx   = lane & 15, tg = lane >> 4;
    const int bx   = blockIdx.x;
    const int n    = bx >> 8;             // codebook-major
    const int t0   = (bx & 255) << 6;
    const int bb   = t0 >> 11, s0 = t0 & (SEQ - 1);
    const int kk   = 2 * n + 1, pad = n;
    const int nrows = 64 + 2 * pad;

    for (int idx = tid; idx < (nrows << 6); idx += 256){
        const int r = idx >> 6, c4 = (idx & 63) << 2;
        const int s = s0 - pad + r;
        float4 v = make_float4(0.f, 0.f, 0.f, 0.f);
        if ((unsigned)s < (unsigned)SEQ)
            v = *reinterpret_cast<const float4*>(&x[(size_t)((bb << 11) + s) * Dm + c4]);
        ushort4 h, l;
        bfsplit(v.x, h.x, l.x); bfsplit(v.y, h.y, l.y);
        bfsplit(v.z, h.z, l.z); bfsplit(v.w, h.w, l.w);
        *reinterpret_cast<ushort4*>(&Ahs[r][c4]) = h;
        *reinterpret_cast<ushort4*>(&Als[r][c4]) = l;
    }
    __syncthreads();

    f32x4 acc[4][4];
    #pragma unroll
    for (int rb = 0; rb < 4; ++rb)
        #pragma unroll
        for (int cb = 0; cb < 4; ++cb)
            acc[rb][cb] = f32x4{0.f, 0.f, 0.f, 0.f};

    #pragma unroll 1
    for (int dh = 0; dh < kk; ++dh){
        #pragma unroll
        for (int ks = 0; ks < 8; ++ks){
            const int m0 = ks << 5;
            bf16x8 ah[4], al[4];
            #pragma unroll
            for (int rb = 0; rb < 4; ++rb){
                const int row = (rb << 4) + tx + dh;
                ah[rb] = *reinterpret_cast<const bf16x8*>(&Ahs[row][m0 + (tg << 3)]);
                al[rb] = *reinterpret_cast<const bf16x8*>(&Als[row][m0 + (tg << 3)]);
            }
            #pragma unroll
            for (int cb = 0; cb < 4; ++cb){
                const int d0 = (w << 6) + (cb << 4);
                if (m0 <= d0 + 143 && m0 >= d0 - 158){   // band-nonzero (wave-uniform)
                    const size_t gg = ((size_t)((n * 7 + dh) * 256 + d0 + tx) << 8) + m0 + (tg << 3);
                    const bf16x8 bh = *reinterpret_cast<const bf16x8*>(&bth[gg]);
                    const bf16x8 bl = *reinterpret_cast<const bf16x8*>(&btl[gg]);
                    #pragma unroll
                    for (int rb = 0; rb < 4; ++rb){
                        acc[rb][cb] = __builtin_amdgcn_mfma_f32_16x16x32_bf16(ah[rb], bh, acc[rb][cb], 0, 0, 0);
                        acc[rb][cb] = __builtin_amdgcn_mfma_f32_16x16x32_bf16(ah[rb], bl, acc[rb][cb], 0, 0, 0);
                        acc[rb][cb] = __builtin_amdgcn_mfma_f32_16x16x32_bf16(al[rb], bh, acc[rb][cb], 0, 0, 0);
                    }
                }
            }
        }
    }

    const float* bP[4] = { b0, b1, b2, b3 };
    const float bias = bP[n][0];
    #pragma unroll
    for (int rb = 0; rb < 4; ++rb)
        #pragma unroll
        for (int cb = 0; cb < 4; ++cb)
            #pragma unroll
            for (int r = 0; r < 4; ++r){
                const int trow = (rb << 4) + (tg << 2) + r;
                const int d    = (w << 6) + (cb << 4) + tx;
                const float v  = fmaxf(acc[rb][cb][r] + bias, 0.f);
                const size_t oidx = (size_t)(t0 + trow) * 1024 + (n << 8) + d;
                ic[oidx] = v;
                __hip_bfloat16 bh = __float2bfloat16(v);
                ich[oidx] = *reinterpret_cast<unsigned short*>(&bh);
            }
}

// ---------------------------------------------------------------- VQ argmin v9: hi-only ranking
// dist_obs = e2 - 2*sum(ah*bh); error sigma ~0.1 -> TAUQ=0.8 (8 sigma) flags all
// candidates for exact f64 re-rank. 1/3 the MFMA, 1/2 the streams of v7.
__global__ __launch_bounds__(256) void k_vq(
    const unsigned short* __restrict__ ich,
    const unsigned short* __restrict__ ebh,
    const float* __restrict__ e2g, int* __restrict__ idx_ws, float* __restrict__ am,
    int* __restrict__ cnt, int2* __restrict__ flags)
{
    __shared__ alignas(16) unsigned short Ahs[64][264];

    const int tid  = threadIdx.x;
    const int lane = tid & 63;
    const int w    = tid >> 6;
    const int tx   = lane & 15, tg = lane >> 4;
    const int bx   = blockIdx.x;
    const int n    = bx >> 8;             // codebook-major
    const int t0   = (bx & 255) << 6;

    // ---- stage A (pre-split hi): 64 rows x 256, plain vector copy
    #pragma unroll
    for (int i = 0; i < 8; ++i){
        const int idx = tid + (i << 8);            // 0..2047 over 64x32 us8-chunks
        const int row = idx >> 5, ch = idx & 31;
        *reinterpret_cast<us8*>(&Ahs[row][ch << 3]) =
            *reinterpret_cast<const us8*>(&ich[(size_t)(t0 + row) * 1024 + (n << 8) + (ch << 3)]);
    }
    __syncthreads();

    float mn[16], mn2[16]; int mi[16];
    #pragma unroll
    for (int s = 0; s < 16; ++s){ mn[s] = 3.4e38f; mn2[s] = 3.4e38f; mi[s] = 0; }

    #pragma unroll 1
    for (int ec = 0; ec < 4; ++ec){
        f32x4 acc[4][4];
        #pragma unroll
        for (int rb = 0; rb < 4; ++rb)
            #pragma unroll
            for (int cb = 0; cb < 4; ++cb)
                acc[rb][cb] = f32x4{0.f, 0.f, 0.f, 0.f};

        #pragma unroll
        for (int ks = 0; ks < 8; ++ks){
            bf16x8 bh[4];
            #pragma unroll
            for (int cb = 0; cb < 4; ++cb){
                const int e = (w << 8) + (ec << 6) + (cb << 4) + tx;
                bh[cb] = *reinterpret_cast<const bf16x8*>(
                    &ebh[((size_t)((n << 10) + e) << 8) + (ks << 5) + (tg << 3)]);
            }
            bf16x8 ah[4];
            #pragma unroll
            for (int rb = 0; rb < 4; ++rb)
                ah[rb] = *reinterpret_cast<const bf16x8*>(&Ahs[(rb << 4) + tx][(ks << 5) + (tg << 3)]);
            #pragma unroll
            for (int rb = 0; rb < 4; ++rb)
                #pragma unroll
                for (int cb = 0; cb < 4; ++cb)
                    acc[rb][cb] = __builtin_amdgcn_mfma_f32_16x16x32_bf16(ah[rb], bh[cb], acc[rb][cb], 0, 0, 0);
        }

        #pragma unroll
        for (int cb = 0; cb < 4; ++cb){
            const int e = (w << 8) + (ec << 6) + (cb << 4) + tx;
            const float ee = e2g[(n << 10) + e];
            #pragma unroll
            for (int rb = 0; rb < 4; ++rb)
                #pragma unroll
                for (int r = 0; r < 4; ++r){
                    const float v = fmaf(-2.f, acc[rb][cb][r], ee);
                    const int s = (rb << 2) + r;
                    if (v < mn[s]){ mn2[s] = mn[s]; mn[s] = v; mi[s] = e; }
                    else if (v < mn2[s]){ mn2[s] = v; }
                }
        }
    }

    #pragma unroll
    for (int sft = 1; sft < 16; sft <<= 1){
        #pragma unroll
        for (int s = 0; s < 16; ++s){
            const float om  = __shfl_xor(mn[s],  sft, 64);
            const float om2 = __shfl_xor(mn2[s], sft, 64);
            const int   oi  = __shfl_xor(mi[s],  sft, 64);
            if (om < mn[s] || (om == mn[s] && oi < mi[s])){
                mn2[s] = fminf(mn[s], om2);
                mn[s] = om; mi[s] = oi;
            } else {
                mn2[s] = fminf(mn2[s], om);
            }
        }
    }
    __syncthreads();
    float* redMn  = reinterpret_cast<float*>(&Ahs[0][0]);
    float* redMn2 = redMn + 256;
    int*   redMi  = reinterpret_cast<int*>(redMn + 512);
    if (tx == 0){
        #pragma unroll
        for (int rb = 0; rb < 4; ++rb)
            #pragma unroll
            for (int r = 0; r < 4; ++r){
                const int row = (rb << 4) + (tg << 2) + r;
                const int s = (rb << 2) + r;
                redMn [(w << 6) + row] = mn[s];
                redMn2[(w << 6) + row] = mn2[s];
                redMi [(w << 6) + row] = mi[s];
            }
    }
    __syncthreads();
    if (tid < 64){
        const int row = tid;
        float bmn = redMn[row], bmn2 = redMn2[row];
        int   bmi = redMi[row];
        #pragma unroll
        for (int wv = 1; wv < 4; ++wv){
            const float om  = redMn [(wv << 6) + row];
            const float om2 = redMn2[(wv << 6) + row];
            const int   oi  = redMi [(wv << 6) + row];
            if (om < bmn || (om == bmn && oi < bmi)){
                bmn2 = fminf(bmn, om2);
                bmn = om; bmi = oi;
            } else {
                bmn2 = fminf(bmn2, om);
            }
        }
        const int t = t0 + row;
        idx_ws[t * 4 + n] = bmi;
        am[(size_t)t * 4 + n] = (float)bmi;
        if (bmn2 - bmn < TAUQ){
            const int pos = atomicAdd(cnt, 1);
            if (pos < FLAGCAP) flags[pos] = make_int2(t, n);
        }
    }
}

// ---------------------------------------------------------------- f64 re-rank v2 (parallel)
__global__ __launch_bounds__(256) void k_fix(
    const float* __restrict__ x,
    const float* __restrict__ w0, const float* __restrict__ w1,
    const float* __restrict__ w2, const float* __restrict__ w3,
    const float* __restrict__ b0, const float* __restrict__ b1,
    const float* __restrict__ b2, const float* __restrict__ b3,
    const float* __restrict__ embT,
    const int* __restrict__ cnt, const int2* __restrict__ flags,
    int* __restrict__ idx_ws, float* __restrict__ am)
{
    __shared__ double xs[7][Dm];
    __shared__ double fl[Dm];
    __shared__ double rD[4];
    __shared__ int    rE[4];
    const int tid = threadIdx.x;
    const int lane = tid & 63, w = tid >> 6;
    const int total = (*cnt < FLAGCAP) ? *cnt : FLAGCAP;
    const float* wP[4] = { w0, w1, w2, w3 };
    const float* bP[4] = { b0, b1, b2, b3 };

    for (int item = blockIdx.x; item < total; item += gridDim.x){
        const int2 f = flags[item];
        const int t = f.x, n = f.y;
        const int bb = t >> 11, s = t & (SEQ - 1);
        const int k = 2 * n + 1, pad = n;
        for (int idx = tid; idx < (k << 8); idx += 256){
            const int r = idx >> 8, m = idx & 255;
            const int sr = s - pad + r;
            xs[r][m] = ((unsigned)sr < (unsigned)SEQ)
                       ? (double)x[(size_t)((bb << 11) + sr) * Dm + m] : 0.0;
        }
        __syncthreads();
        {
            const int d = tid;
            double a0 = (double)bP[n][0], a1 = 0.0;
            for (int dh = 0; dh < k; ++dh){
                const float* wr = wP[n] + dh * Dm;
                const int lo = (d - 127 < 0) ? 0 : d - 127;
                const int hi = (d + 129 > Dm) ? Dm : d + 129;
                int m = lo;
                for (; m + 1 < hi; m += 2){
                    a0 += xs[dh][m]     * (double)wr[m - d + 127];
                    a1 += xs[dh][m + 1] * (double)wr[m - d + 128];
                }
                if (m < hi) a0 += xs[dh][m] * (double)wr[m - d + 127];
            }
            const double acc = a0 + a1;
            fl[d] = (acc > 0.0) ? acc : 0.0;
        }
        __syncthreads();
        double bD = 1e300; int bE = 0;
        const float* ebase = embT + (size_t)n * NE * Dm;
        const int d4 = lane << 2;
        const double f0 = fl[d4], f1 = fl[d4 + 1], f2 = fl[d4 + 2], f3 = fl[d4 + 3];
        for (int j = 0; j < 256; ++j){
            const int e = (j << 2) + w;
            const float4 v = *reinterpret_cast<const float4*>(&ebase[(size_t)e * Dm + d4]);
            const double v0 = v.x, v1 = v.y, v2 = v.z, v3 = v.w;
            double dot = v0 * f0 + v1 * f1 + v2 * f2 + v3 * f3;
            double ee  = v0 * v0 + v1 * v1 + v2 * v2 + v3 * v3;
            #pragma unroll
            for (int sft = 1; sft < 64; sft <<= 1){
                dot += __shfl_xor(dot, sft, 64);
                ee  += __shfl_xor(ee,  sft, 64);
            }
            const double dist = ee - 2.0 * dot;
            if (dist < bD || (dist == bD && e < bE)){ bD = dist; bE = e; }
        }
        if (lane == 0){ rD[w] = bD; rE[w] = bE; }
        __syncthreads();
        if (tid == 0){
            #pragma unroll
            for (int wv = 1; wv < 4; ++wv)
                if (rD[wv] < rD[0] || (rD[wv] == rD[0] && rE[wv] < rE[0])){
                    rD[0] = rD[wv]; rE[0] = rE[wv];
                }
            idx_ws[t * 4 + n] = rE[0];
            am[(size_t)t * 4 + n] = (float)rE[0];
        }
        __syncthreads();
    }
}

// ---------------------------------------------------------------- gather + gate + z_q
__global__ __launch_bounds__(256) void k_final(
    const int* __restrict__ idx_ws, const float* __restrict__ embT,
    const float* __restrict__ gw, const float* __restrict__ gb,
    float* __restrict__ qc, float* __restrict__ zq)
{
    __shared__ float gws[4][Dm];
    const int tid = threadIdx.x;
    for (int i = tid; i < 4 * Dm; i += 256) gws[i >> 8][i & 255] = gw[i];
    __syncthreads();
    const int t = (blockIdx.x << 2) + (tid >> 6);
    const int lane = tid & 63, d0 = lane << 2;

    float q[4][4];
    #pragma unroll
    for (int n = 0; n < 4; ++n){
        const int e = idx_ws[t * 4 + n];
        const float4 v = *reinterpret_cast<const float4*>(
            &embT[((size_t)n * NE + e) * Dm + d0]);
        q[n][0] = v.x; q[n][1] = v.y; q[n][2] = v.z; q[n][3] = v.w;
        *reinterpret_cast<float4*>(&qc[(size_t)t * 1024 + n * Dm + d0]) = v;
    }
    float part[4];
    #pragma unroll
    for (int n = 0; n < 4; ++n){
        part[n] = q[0][0] * gws[n][d0]     + q[0][1] * gws[n][d0 + 1]
                + q[0][2] * gws[n][d0 + 2] + q[0][3] * gws[n][d0 + 3];
    }
    #pragma unroll
    for (int s = 1; s < 64; s <<= 1){
        #pragma unroll
        for (int n = 0; n < 4; ++n) part[n] += __shfl_xor(part[n], s, 64);
    }
    float lg[4];
    #pragma unroll
    for (int n = 0; n < 4; ++n) lg[n] = part[n] + gb[n];
    const float mx = fmaxf(fmaxf(lg[0], lg[1]), fmaxf(lg[2], lg[3]));
    float ex[4], ssum = 0.f;
    #pragma unroll
    for (int n = 0; n < 4; ++n){ ex[n] = expf(lg[n] - mx); ssum += ex[n]; }
    const float inv = 1.f / ssum;
    float z[4];
    #pragma unroll
    for (int dd = 0; dd < 4; ++dd)
        z[dd] = (ex[0] * q[0][dd] + ex[1] * q[1][dd] + ex[2] * q[2][dd] + ex[3] * q[3][dd]) * inv;
    *reinterpret_cast<float4*>(&zq[(size_t)t * Dm + d0]) =
        make_float4(z[0], z[1], z[2], z[3]);
}

// ---------------------------------------------------------------- launch
extern "C" void kernel_launch(void* const* d_in, const int* in_sizes, int n_in,
                              void* d_out, int out_size, void* d_ws, size_t ws_size,
                              hipStream_t stream)
{
    const float* x   = (const float*)d_in[0];
    const float* w0  = (const float*)d_in[1];
    const float* b0  = (const float*)d_in[2];
    const float* w1  = (const float*)d_in[3];
    const float* b1  = (const float*)d_in[4];
    const float* w2  = (const float*)d_in[5];
    const float* b2  = (const float*)d_in[6];
    const float* w3  = (const float*)d_in[7];
    const float* b3  = (const float*)d_in[8];
    const float* emb = (const float*)d_in[9];
    const float* gw  = (const float*)d_in[10];
    const float* gb  = (const float*)d_in[11];

    float* out = (float*)d_out;
    float* zq = out;                    //  4,194,304  (T x 256)
    float* am = out + 4194304;          //     65,536  (T x 4)
    float* ic = out + 4259840;          // 16,777,216  (T x 1024)
    float* qc = out + 21037056;         // 16,777,216  (T x 1024)
    // qc region doubles as pre-split bf16-hi scratch (fully overwritten by k_final)
    unsigned short* ich = (unsigned short*)qc;   // 16,777,216 ushorts

    float* ws    = (float*)d_ws;
    float* embT  = ws;                                      // [4][1024][256] f32
    float* e2    = ws + 1048576;                            // [4][1024]      f32
    int*   idxs  = (int*)(ws + 1052672);                    // [16384][4]     i32
    int*   cnt   = (int*)(ws + 1118208);                    // 1 i32
    int2*  flags = (int2*)(ws + 1118212);                   // FLAGCAP int2 -> ends 1380356
    unsigned short* ebh = (unsigned short*)(ws + 1380360);  // [4][1024][256] bf16 hi (524288 f)
    unsigned short* ebl = (unsigned short*)(ws + 1904648);  // [4][1024][256] bf16 lo (524288 f)
    unsigned short* bth = (unsigned short*)(ws + 2428936);  // [4][7][256][256] bf16 hi (917504 f)
    unsigned short* btl = (unsigned short*)(ws + 3346440);  // [4][7][256][256] bf16 lo (917504 f)

    hipLaunchKernelGGL(k_transpose, dim3(32, 8, 4), dim3(32, 8), 0, stream, emb, embT);
    hipLaunchKernelGGL(k_e2,        dim3(4, 4),     dim3(256),   0, stream, emb, e2, cnt);
    hipLaunchKernelGGL(k_cvt,       dim3(1024),     dim3(256),   0, stream, embT, ebh, ebl);
    hipLaunchKernelGGL(k_prep,      dim3(7, 4),     dim3(256),   0, stream,
                       w0, w1, w2, w3, bth, btl);
    hipLaunchKernelGGL(k_conv,      dim3(1024),     dim3(256),   0, stream,
                       x, bth, btl, b0, b1, b2, b3, ic, ich);
    hipLaunchKernelGGL(k_vq,        dim3(1024),     dim3(256),   0, stream,
                       ich, ebh, e2, idxs, am, cnt, flags);
    hipLaunchKernelGGL(k_fix,       dim3(2048),     dim3(256),   0, stream,
                       x, w0, w1, w2, w3, b0, b1, b2, b3, embT, cnt, flags, idxs, am);
    hipLaunchKernelGGL(k_final,     dim3(4096),     dim3(256),   0, stream,
                       idxs, embT, gw, gb, qc, zq);
}

// Round 15
// 626.109 us; speedup vs baseline: 3.2791x; 3.2791x over previous
//
#include <hip/hip_runtime.h>
#include <hip/hip_bf16.h>

#define SEQ   2048
#define Dm    256
#define NE    1024
#define TT    16384   // B*S = 8*2048
#define TAU   0.02f   // near-tie gap threshold (~100 sigma of 3-term split-bf16 error)
#define FLAGCAP 131072

typedef __attribute__((ext_vector_type(8))) short          bf16x8;
typedef __attribute__((ext_vector_type(4))) float          f32x4;
typedef __attribute__((ext_vector_type(8))) unsigned short us8;

__device__ __forceinline__ void bfsplit(float x, unsigned short& h, unsigned short& l){
    __hip_bfloat16 bh = __float2bfloat16(x);
    h = *reinterpret_cast<unsigned short*>(&bh);
    union { unsigned u; float f; } c; c.u = (unsigned)h << 16;
    __hip_bfloat16 bl = __float2bfloat16(x - c.f);
    l = *reinterpret_cast<unsigned short*>(&bl);
}

// ---------------------------------------------------------------- transpose
__global__ void k_transpose(const float* __restrict__ emb, float* __restrict__ embT){
    __shared__ float tile[32][33];
    const int n  = blockIdx.z;
    const int e0 = blockIdx.x << 5, d0 = blockIdx.y << 5;
    const int tx = threadIdx.x, ty = threadIdx.y;
    const float* src = emb + (size_t)n * Dm * NE;
    float* dst = embT + (size_t)n * NE * Dm;
    #pragma unroll
    for (int i = ty; i < 32; i += 8)
        tile[i][tx] = src[(size_t)(d0 + i) * NE + e0 + tx];
    __syncthreads();
    #pragma unroll
    for (int i = ty; i < 32; i += 8)
        dst[(size_t)(e0 + i) * Dm + d0 + tx] = tile[tx][i];
}

// ---------------------------------------------------------------- e2 norms (+ zero flag counter)
__global__ void k_e2(const float* __restrict__ emb, float* __restrict__ e2,
                     int* __restrict__ cnt){
    if (blockIdx.x == 0 && blockIdx.y == 0 && threadIdx.x == 0) *cnt = 0;
    const int n = blockIdx.y;
    const int e = (blockIdx.x << 8) + threadIdx.x;
    const float* p = emb + (size_t)n * Dm * NE + e;
    float s = 0.f;
    #pragma unroll 8
    for (int d = 0; d < Dm; ++d){ float v = p[(size_t)d * NE]; s = fmaf(v, v, s); }
    e2[n * NE + e] = s;
}

// ---------------------------------------------------------------- split embT into bf16 hi/lo
__global__ __launch_bounds__(256) void k_cvt(const float* __restrict__ embT,
                                             unsigned short* __restrict__ eh,
                                             unsigned short* __restrict__ el){
    const int i = ((blockIdx.x << 8) + threadIdx.x) << 2;
    const float4 v = *reinterpret_cast<const float4*>(&embT[i]);
    ushort4 h, l;
    bfsplit(v.x, h.x, l.x); bfsplit(v.y, h.y, l.y);
    bfsplit(v.z, h.z, l.z); bfsplit(v.w, h.w, l.w);
    *reinterpret_cast<ushort4*>(&eh[i]) = h;
    *reinterpret_cast<ushort4*>(&el[i]) = l;
}

// ---------------------------------------------------------------- prep banded conv weights
__global__ __launch_bounds__(256) void k_prep(
    const float* __restrict__ w0, const float* __restrict__ w1,
    const float* __restrict__ w2, const float* __restrict__ w3,
    unsigned short* __restrict__ bth, unsigned short* __restrict__ btl)
{
    const int dh = blockIdx.x;            // 0..6
    const int n  = blockIdx.y;            // 0..3
    const int kk = 2 * n + 1;
    if (dh >= kk) return;
    const float* wr[4] = { w0, w1, w2, w3 };
    const float* wp = wr[n] + dh * Dm;
    const int d = threadIdx.x;
    const size_t base = ((size_t)((n * 7 + dh) * 256 + d)) << 8;
    for (int mc = 0; mc < 256; mc += 4){
        ushort4 h, l;
        #pragma unroll
        for (int q = 0; q < 4; ++q){
            const int j = mc + q - d + 127;
            const float v = ((unsigned)j < 256u) ? wp[j] : 0.f;
            unsigned short hh, ll;
            bfsplit(v, hh, ll);
            (&h.x)[q] = hh; (&l.x)[q] = ll;
        }
        *reinterpret_cast<ushort4*>(&bth[base + mc]) = h;
        *reinterpret_cast<ushort4*>(&btl[base + mc]) = l;
    }
}

// ---------------------------------------------------------------- conv via split-bf16 MFMA
// Codebook-major. Emits f32 ic and pre-split bf16 hi/lo (ich/icl) for k_vq.
__global__ __launch_bounds__(256, 2) void k_conv(
    const float* __restrict__ x,
    const unsigned short* __restrict__ bth, const unsigned short* __restrict__ btl,
    const float* __restrict__ b0, const float* __restrict__ b1,
    const float* __restrict__ b2, const float* __restrict__ b3,
    float* __restrict__ ic,
    unsigned short* __restrict__ ich, unsigned short* __restrict__ icl)
{
    __shared__ alignas(16) unsigned short Ahs[70][264];
    __shared__ alignas(16) unsigned short Als[70][264];

    const int tid  = threadIdx.x;
    const int lane = tid & 63;
    const int w    = tid >> 6;
    const int tx   = lane & 15, tg = lane >> 4;
    const int bx   = blockIdx.x;
    const int n    = bx >> 8;             // codebook-major
    const int t0   = (bx & 255) << 6;
    const int bb   = t0 >> 11, s0 = t0 & (SEQ - 1);
    const int kk   = 2 * n + 1, pad = n;
    const int nrows = 64 + 2 * pad;

    for (int idx = tid; idx < (nrows << 6); idx += 256){
        const int r = idx >> 6, c4 = (idx & 63) << 2;
        const int s = s0 - pad + r;
        float4 v = make_float4(0.f, 0.f, 0.f, 0.f);
        if ((unsigned)s < (unsigned)SEQ)
            v = *reinterpret_cast<const float4*>(&x[(size_t)((bb << 11) + s) * Dm + c4]);
        ushort4 h, l;
        bfsplit(v.x, h.x, l.x); bfsplit(v.y, h.y, l.y);
        bfsplit(v.z, h.z, l.z); bfsplit(v.w, h.w, l.w);
        *reinterpret_cast<ushort4*>(&Ahs[r][c4]) = h;
        *reinterpret_cast<ushort4*>(&Als[r][c4]) = l;
    }
    __syncthreads();

    f32x4 acc[4][4];
    #pragma unroll
    for (int rb = 0; rb < 4; ++rb)
        #pragma unroll
        for (int cb = 0; cb < 4; ++cb)
            acc[rb][cb] = f32x4{0.f, 0.f, 0.f, 0.f};

    #pragma unroll 1
    for (int dh = 0; dh < kk; ++dh){
        #pragma unroll
        for (int ks = 0; ks < 8; ++ks){
            const int m0 = ks << 5;
            bf16x8 ah[4], al[4];
            #pragma unroll
            for (int rb = 0; rb < 4; ++rb){
                const int row = (rb << 4) + tx + dh;
                ah[rb] = *reinterpret_cast<const bf16x8*>(&Ahs[row][m0 + (tg << 3)]);
                al[rb] = *reinterpret_cast<const bf16x8*>(&Als[row][m0 + (tg << 3)]);
            }
            #pragma unroll
            for (int cb = 0; cb < 4; ++cb){
                const int d0 = (w << 6) + (cb << 4);
                if (m0 <= d0 + 143 && m0 >= d0 - 158){   // band-nonzero (wave-uniform)
                    const size_t gg = ((size_t)((n * 7 + dh) * 256 + d0 + tx) << 8) + m0 + (tg << 3);
                    const bf16x8 bh = *reinterpret_cast<const bf16x8*>(&bth[gg]);
                    const bf16x8 bl = *reinterpret_cast<const bf16x8*>(&btl[gg]);
                    #pragma unroll
                    for (int rb = 0; rb < 4; ++rb){
                        acc[rb][cb] = __builtin_amdgcn_mfma_f32_16x16x32_bf16(ah[rb], bh, acc[rb][cb], 0, 0, 0);
                        acc[rb][cb] = __builtin_amdgcn_mfma_f32_16x16x32_bf16(ah[rb], bl, acc[rb][cb], 0, 0, 0);
                        acc[rb][cb] = __builtin_amdgcn_mfma_f32_16x16x32_bf16(al[rb], bh, acc[rb][cb], 0, 0, 0);
                    }
                }
            }
        }
    }

    const float* bP[4] = { b0, b1, b2, b3 };
    const float bias = bP[n][0];
    #pragma unroll
    for (int rb = 0; rb < 4; ++rb)
        #pragma unroll
        for (int cb = 0; cb < 4; ++cb)
            #pragma unroll
            for (int r = 0; r < 4; ++r){
                const int trow = (rb << 4) + (tg << 2) + r;
                const int d    = (w << 6) + (cb << 4) + tx;
                const float v  = fmaxf(acc[rb][cb][r] + bias, 0.f);
                const size_t oidx = (size_t)(t0 + trow) * 1024 + (n << 8) + d;
                ic[oidx] = v;
                unsigned short hh, ll;
                bfsplit(v, hh, ll);
                ich[oidx] = hh; icl[oidx] = ll;
            }
}

// ---------------------------------------------------------------- VQ argmin v10
// Round-10 v5 dbuf structure (fastest measured) with A plain-copied from
// pre-split ich/icl (no bfsplit prologue). 3-term split-bf16, TAU=0.02.
#define LOADB(BH, BL, ksv) { \
    _Pragma("unroll") \
    for (int cb = 0; cb < 4; ++cb){ \
        const size_t gg = ebbase[cb] + ((ksv) << 5); \
        BH[cb] = *reinterpret_cast<const bf16x8*>(&ebh[gg]); \
        BL[cb] = *reinterpret_cast<const bf16x8*>(&ebl[gg]); \
    } \
}
#define DOSTEP(BH, BL, ksv) { \
    bf16x8 ah[4], al[4]; \
    _Pragma("unroll") \
    for (int rb = 0; rb < 4; ++rb){ \
        ah[rb] = *reinterpret_cast<const bf16x8*>(&Ahs[(rb << 4) + tx][((ksv) << 5) + (tg << 3)]); \
        al[rb] = *reinterpret_cast<const bf16x8*>(&Als[(rb << 4) + tx][((ksv) << 5) + (tg << 3)]); \
    } \
    _Pragma("unroll") \
    for (int rb = 0; rb < 4; ++rb){ \
        _Pragma("unroll") \
        for (int cb = 0; cb < 4; ++cb){ \
            acc[rb][cb] = __builtin_amdgcn_mfma_f32_16x16x32_bf16(ah[rb], BH[cb], acc[rb][cb], 0, 0, 0); \
            acc[rb][cb] = __builtin_amdgcn_mfma_f32_16x16x32_bf16(ah[rb], BL[cb], acc[rb][cb], 0, 0, 0); \
            acc[rb][cb] = __builtin_amdgcn_mfma_f32_16x16x32_bf16(al[rb], BH[cb], acc[rb][cb], 0, 0, 0); \
        } \
    } \
}

__global__ __launch_bounds__(256, 2) void k_vq(
    const unsigned short* __restrict__ ich, const unsigned short* __restrict__ icl,
    const unsigned short* __restrict__ ebh, const unsigned short* __restrict__ ebl,
    const float* __restrict__ e2g, int* __restrict__ idx_ws, float* __restrict__ am,
    int* __restrict__ cnt, int2* __restrict__ flags)
{
    __shared__ alignas(16) unsigned short Ahs[64][264];
    __shared__ alignas(16) unsigned short Als[64][264];

    const int tid  = threadIdx.x;
    const int lane = tid & 63;
    const int w    = tid >> 6;
    const int tx   = lane & 15, tg = lane >> 4;
    const int bx   = blockIdx.x;
    const int n    = bx >> 8;             // codebook-major
    const int t0   = (bx & 255) << 6;

    // ---- stage A from pre-split hi/lo (plain vector copies)
    #pragma unroll
    for (int i = 0; i < 8; ++i){
        const int idx = tid + (i << 8);          // 0..2047 over 64 rows x 32 chunks
        const int row = idx >> 5, ch = (idx & 31) << 3;
        const size_t g = (size_t)(t0 + row) * 1024 + (n << 8) + ch;
        *reinterpret_cast<us8*>(&Ahs[row][ch]) = *reinterpret_cast<const us8*>(&ich[g]);
        *reinterpret_cast<us8*>(&Als[row][ch]) = *reinterpret_cast<const us8*>(&icl[g]);
    }
    __syncthreads();

    float mn[16], mn2[16]; int mi[16];
    #pragma unroll
    for (int s = 0; s < 16; ++s){ mn[s] = 3.4e38f; mn2[s] = 3.4e38f; mi[s] = 0; }

    #pragma unroll 1
    for (int ec = 0; ec < 4; ++ec){
        f32x4 acc[4][4];
        #pragma unroll
        for (int rb = 0; rb < 4; ++rb)
            #pragma unroll
            for (int cb = 0; cb < 4; ++cb)
                acc[rb][cb] = f32x4{0.f, 0.f, 0.f, 0.f};

        size_t ebbase[4];
        #pragma unroll
        for (int cb = 0; cb < 4; ++cb){
            const int e = (w << 8) + (ec << 6) + (cb << 4) + tx;
            ebbase[cb] = ((size_t)((n << 10) + e) << 8) + (tg << 3);
        }

        bf16x8 bh0[4], bl0[4], bh1[4], bl1[4];
        LOADB(bh0, bl0, 0);
        #pragma unroll
        for (int kp = 0; kp < 4; ++kp){
            LOADB(bh1, bl1, 2 * kp + 1);
            DOSTEP(bh0, bl0, 2 * kp);
            if (kp < 3) LOADB(bh0, bl0, 2 * kp + 2);
            DOSTEP(bh1, bl1, 2 * kp + 1);
        }

        #pragma unroll
        for (int cb = 0; cb < 4; ++cb){
            const int e = (w << 8) + (ec << 6) + (cb << 4) + tx;
            const float ee = e2g[(n << 10) + e];
            #pragma unroll
            for (int rb = 0; rb < 4; ++rb)
                #pragma unroll
                for (int r = 0; r < 4; ++r){
                    const float v = fmaf(-2.f, acc[rb][cb][r], ee);
                    const int s = (rb << 2) + r;
                    if (v < mn[s]){ mn2[s] = mn[s]; mn[s] = v; mi[s] = e; }
                    else if (v < mn2[s]){ mn2[s] = v; }
                }
        }
    }

    #pragma unroll
    for (int sft = 1; sft < 16; sft <<= 1){
        #pragma unroll
        for (int s = 0; s < 16; ++s){
            const float om  = __shfl_xor(mn[s],  sft, 64);
            const float om2 = __shfl_xor(mn2[s], sft, 64);
            const int   oi  = __shfl_xor(mi[s],  sft, 64);
            if (om < mn[s] || (om == mn[s] && oi < mi[s])){
                mn2[s] = fminf(mn[s], om2);
                mn[s] = om; mi[s] = oi;
            } else {
                mn2[s] = fminf(mn2[s], om);
            }
        }
    }
    __syncthreads();
    float* redMn  = reinterpret_cast<float*>(&Ahs[0][0]);
    float* redMn2 = redMn + 256;
    int*   redMi  = reinterpret_cast<int*>(redMn + 512);
    if (tx == 0){
        #pragma unroll
        for (int rb = 0; rb < 4; ++rb)
            #pragma unroll
            for (int r = 0; r < 4; ++r){
                const int row = (rb << 4) + (tg << 2) + r;
                const int s = (rb << 2) + r;
                redMn [(w << 6) + row] = mn[s];
                redMn2[(w << 6) + row] = mn2[s];
                redMi [(w << 6) + row] = mi[s];
            }
    }
    __syncthreads();
    if (tid < 64){
        const int row = tid;
        float bmn = redMn[row], bmn2 = redMn2[row];
        int   bmi = redMi[row];
        #pragma unroll
        for (int wv = 1; wv < 4; ++wv){
            const float om  = redMn [(wv << 6) + row];
            const float om2 = redMn2[(wv << 6) + row];
            const int   oi  = redMi [(wv << 6) + row];
            if (om < bmn || (om == bmn && oi < bmi)){
                bmn2 = fminf(bmn, om2);
                bmn = om; bmi = oi;
            } else {
                bmn2 = fminf(bmn2, om);
            }
        }
        const int t = t0 + row;
        idx_ws[t * 4 + n] = bmi;
        am[(size_t)t * 4 + n] = (float)bmi;
        if (bmn2 - bmn < TAU){
            const int pos = atomicAdd(cnt, 1);
            if (pos < FLAGCAP) flags[pos] = make_int2(t, n);
        }
    }
}

// ---------------------------------------------------------------- f64 re-rank v3
// Thread-per-embedding distance pass (no shuffles in hot loop), LDS-staged conv.
__global__ __launch_bounds__(256) void k_fix(
    const float* __restrict__ x,
    const float* __restrict__ w0, const float* __restrict__ w1,
    const float* __restrict__ w2, const float* __restrict__ w3,
    const float* __restrict__ b0, const float* __restrict__ b1,
    const float* __restrict__ b2, const float* __restrict__ b3,
    const float* __restrict__ embT,
    const int* __restrict__ cnt, const int2* __restrict__ flags,
    int* __restrict__ idx_ws, float* __restrict__ am)
{
    __shared__ double xs[7][Dm];
    __shared__ double fl[Dm];
    __shared__ double rD[4];
    __shared__ int    rE[4];
    const int tid = threadIdx.x;
    const int lane = tid & 63, w = tid >> 6;
    const int total = (*cnt < FLAGCAP) ? *cnt : FLAGCAP;
    const float* wP[4] = { w0, w1, w2, w3 };
    const float* bP[4] = { b0, b1, b2, b3 };

    for (int item = blockIdx.x; item < total; item += gridDim.x){
        const int2 f = flags[item];
        const int t = f.x, n = f.y;
        const int bb = t >> 11, s = t & (SEQ - 1);
        const int k = 2 * n + 1, pad = n;
        // ---- stage x window (coalesced) as f64
        for (int idx = tid; idx < (k << 8); idx += 256){
            const int r = idx >> 8, m = idx & 255;
            const int sr = s - pad + r;
            xs[r][m] = ((unsigned)sr < (unsigned)SEQ)
                       ? (double)x[(size_t)((bb << 11) + sr) * Dm + m] : 0.0;
        }
        __syncthreads();
        // ---- f64 conv from LDS, thread d, 2 accumulators
        {
            const int d = tid;
            double a0 = (double)bP[n][0], a1 = 0.0;
            for (int dh = 0; dh < k; ++dh){
                const float* wr = wP[n] + dh * Dm;
                const int lo = (d - 127 < 0) ? 0 : d - 127;
                const int hi = (d + 129 > Dm) ? Dm : d + 129;
                int m = lo;
                for (; m + 1 < hi; m += 2){
                    a0 += xs[dh][m]     * (double)wr[m - d + 127];
                    a1 += xs[dh][m + 1] * (double)wr[m - d + 128];
                }
                if (m < hi) a0 += xs[dh][m] * (double)wr[m - d + 127];
            }
            const double acc = a0 + a1;
            fl[d] = (acc > 0.0) ? acc : 0.0;
        }
        __syncthreads();
        // ---- distances: thread-per-embedding, f64 scalar accumulation, no shuffles
        double bD = 1e300; int bE = 0;
        const float* ebase = embT + (size_t)n * NE * Dm;
        #pragma unroll 1
        for (int p = 0; p < 4; ++p){
            const int e = (p << 8) + tid;
            const float4* row = reinterpret_cast<const float4*>(&ebase[(size_t)e * Dm]);
            double d0 = 0.0, d1 = 0.0, s0 = 0.0, s1 = 0.0;
            for (int j = 0; j < 64; j += 2){
                const float4 va = row[j], vb = row[j + 1];
                const int m = j << 2;
                d0 += (double)va.x * fl[m]     + (double)va.y * fl[m + 1]
                    + (double)va.z * fl[m + 2] + (double)va.w * fl[m + 3];
                s0 += (double)va.x * (double)va.x + (double)va.y * (double)va.y
                    + (double)va.z * (double)va.z + (double)va.w * (double)va.w;
                d1 += (double)vb.x * fl[m + 4] + (double)vb.y * fl[m + 5]
                    + (double)vb.z * fl[m + 6] + (double)vb.w * fl[m + 7];
                s1 += (double)vb.x * (double)vb.x + (double)vb.y * (double)vb.y
                    + (double)vb.z * (double)vb.z + (double)vb.w * (double)vb.w;
            }
            const double dist = (s0 + s1) - 2.0 * (d0 + d1);
            if (dist < bD || (dist == bD && e < bE)){ bD = dist; bE = e; }
        }
        // ---- wave reduce (6 steps) + cross-wave merge
        #pragma unroll
        for (int sft = 1; sft < 64; sft <<= 1){
            const double od = __shfl_xor(bD, sft, 64);
            const int    oe = __shfl_xor(bE, sft, 64);
            if (od < bD || (od == bD && oe < bE)){ bD = od; bE = oe; }
        }
        if (lane == 0){ rD[w] = bD; rE[w] = bE; }
        __syncthreads();
        if (tid == 0){
            #pragma unroll
            for (int wv = 1; wv < 4; ++wv)
                if (rD[wv] < rD[0] || (rD[wv] == rD[0] && rE[wv] < rE[0])){
                    rD[0] = rD[wv]; rE[0] = rE[wv];
                }
            idx_ws[t * 4 + n] = rE[0];
            am[(size_t)t * 4 + n] = (float)rE[0];
        }
        __syncthreads();
    }
}

// ---------------------------------------------------------------- gather + gate + z_q
__global__ __launch_bounds__(256) void k_final(
    const int* __restrict__ idx_ws, const float* __restrict__ embT,
    const float* __restrict__ gw, const float* __restrict__ gb,
    float* __restrict__ qc, float* __restrict__ zq)
{
    __shared__ float gws[4][Dm];
    const int tid = threadIdx.x;
    for (int i = tid; i < 4 * Dm; i += 256) gws[i >> 8][i & 255] = gw[i];
    __syncthreads();
    const int t = (blockIdx.x << 2) + (tid >> 6);
    const int lane = tid & 63, d0 = lane << 2;

    float q[4][4];
    #pragma unroll
    for (int n = 0; n < 4; ++n){
        const int e = idx_ws[t * 4 + n];
        const float4 v = *reinterpret_cast<const float4*>(
            &embT[((size_t)n * NE + e) * Dm + d0]);
        q[n][0] = v.x; q[n][1] = v.y; q[n][2] = v.z; q[n][3] = v.w;
        *reinterpret_cast<float4*>(&qc[(size_t)t * 1024 + n * Dm + d0]) = v;
    }
    float part[4];
    #pragma unroll
    for (int n = 0; n < 4; ++n){
        part[n] = q[0][0] * gws[n][d0]     + q[0][1] * gws[n][d0 + 1]
                + q[0][2] * gws[n][d0 + 2] + q[0][3] * gws[n][d0 + 3];
    }
    #pragma unroll
    for (int s = 1; s < 64; s <<= 1){
        #pragma unroll
        for (int n = 0; n < 4; ++n) part[n] += __shfl_xor(part[n], s, 64);
    }
    float lg[4];
    #pragma unroll
    for (int n = 0; n < 4; ++n) lg[n] = part[n] + gb[n];
    const float mx = fmaxf(fmaxf(lg[0], lg[1]), fmaxf(lg[2], lg[3]));
    float ex[4], ssum = 0.f;
    #pragma unroll
    for (int n = 0; n < 4; ++n){ ex[n] = expf(lg[n] - mx); ssum += ex[n]; }
    const float inv = 1.f / ssum;
    float z[4];
    #pragma unroll
    for (int dd = 0; dd < 4; ++dd)
        z[dd] = (ex[0] * q[0][dd] + ex[1] * q[1][dd] + ex[2] * q[2][dd] + ex[3] * q[3][dd]) * inv;
    *reinterpret_cast<float4*>(&zq[(size_t)t * Dm + d0]) =
        make_float4(z[0], z[1], z[2], z[3]);
}

// ---------------------------------------------------------------- launch
extern "C" void kernel_launch(void* const* d_in, const int* in_sizes, int n_in,
                              void* d_out, int out_size, void* d_ws, size_t ws_size,
                              hipStream_t stream)
{
    const float* x   = (const float*)d_in[0];
    const float* w0  = (const float*)d_in[1];
    const float* b0  = (const float*)d_in[2];
    const float* w1  = (const float*)d_in[3];
    const float* b1  = (const float*)d_in[4];
    const float* w2  = (const float*)d_in[5];
    const float* b2  = (const float*)d_in[6];
    const float* w3  = (const float*)d_in[7];
    const float* b3  = (const float*)d_in[8];
    const float* emb = (const float*)d_in[9];
    const float* gw  = (const float*)d_in[10];
    const float* gb  = (const float*)d_in[11];

    float* out = (float*)d_out;
    float* zq = out;                    //  4,194,304  (T x 256)
    float* am = out + 4194304;          //     65,536  (T x 4)
    float* ic = out + 4259840;          // 16,777,216  (T x 1024)
    float* qc = out + 21037056;         // 16,777,216  (T x 1024)
    // qc region doubles as pre-split scratch (fully overwritten by k_final)
    unsigned short* ich = (unsigned short*)qc;   // 16,777,216 ushorts
    unsigned short* icl = ich + 16777216;        // 16,777,216 ushorts

    float* ws    = (float*)d_ws;
    float* embT  = ws;                                      // [4][1024][256] f32
    float* e2    = ws + 1048576;                            // [4][1024]      f32
    int*   idxs  = (int*)(ws + 1052672);                    // [16384][4]     i32
    int*   cnt   = (int*)(ws + 1118208);                    // 1 i32
    int2*  flags = (int2*)(ws + 1118212);                   // FLAGCAP int2 -> ends 1380356
    unsigned short* ebh = (unsigned short*)(ws + 1380360);  // [4][1024][256] bf16 hi (524288 f)
    unsigned short* ebl = (unsigned short*)(ws + 1904648);  // [4][1024][256] bf16 lo (524288 f)
    unsigned short* bth = (unsigned short*)(ws + 2428936);  // [4][7][256][256] bf16 hi (917504 f)
    unsigned short* btl = (unsigned short*)(ws + 3346440);  // [4][7][256][256] bf16 lo (917504 f)

    hipLaunchKernelGGL(k_transpose, dim3(32, 8, 4), dim3(32, 8), 0, stream, emb, embT);
    hipLaunchKernelGGL(k_e2,        dim3(4, 4),     dim3(256),   0, stream, emb, e2, cnt);
    hipLaunchKernelGGL(k_cvt,       dim3(1024),     dim3(256),   0, stream, embT, ebh, ebl);
    hipLaunchKernelGGL(k_prep,      dim3(7, 4),     dim3(256),   0, stream,
                       w0, w1, w2, w3, bth, btl);
    hipLaunchKernelGGL(k_conv,      dim3(1024),     dim3(256),   0, stream,
                       x, bth, btl, b0, b1, b2, b3, ic, ich, icl);
    hipLaunchKernelGGL(k_vq,        dim3(1024),     dim3(256),   0, stream,
                       ich, icl, ebh, ebl, e2, idxs, am, cnt, flags);
    hipLaunchKernelGGL(k_fix,       dim3(2048),     dim3(256),   0, stream,
                       x, w0, w1, w2, w3, b0, b1, b2, b3, embT, cnt, flags, idxs, am);
    hipLaunchKernelGGL(k_final,     dim3(4096),     dim3(256),   0, stream,
                       idxs, embT, gw, gb, qc, zq);
}

// Round 16
// 572.288 us; speedup vs baseline: 3.5875x; 1.0940x over previous
//
#include <hip/hip_runtime.h>
#include <hip/hip_bf16.h>

#define SEQ   2048
#define Dm    256
#define NE    1024
#define TT    16384   // B*S = 8*2048
#define TAU   0.02f   // near-tie gap threshold (~100 sigma of 3-term split-bf16 error)
#define FLAGCAP 131072

typedef __attribute__((ext_vector_type(8))) short          bf16x8;
typedef __attribute__((ext_vector_type(4))) float          f32x4;
typedef __attribute__((ext_vector_type(8))) unsigned short us8;

__device__ __forceinline__ void bfsplit(float x, unsigned short& h, unsigned short& l){
    __hip_bfloat16 bh = __float2bfloat16(x);
    h = *reinterpret_cast<unsigned short*>(&bh);
    union { unsigned u; float f; } c; c.u = (unsigned)h << 16;
    __hip_bfloat16 bl = __float2bfloat16(x - c.f);
    l = *reinterpret_cast<unsigned short*>(&bl);
}

// ---------------------------------------------------------------- transpose
__global__ void k_transpose(const float* __restrict__ emb, float* __restrict__ embT){
    __shared__ float tile[32][33];
    const int n  = blockIdx.z;
    const int e0 = blockIdx.x << 5, d0 = blockIdx.y << 5;
    const int tx = threadIdx.x, ty = threadIdx.y;
    const float* src = emb + (size_t)n * Dm * NE;
    float* dst = embT + (size_t)n * NE * Dm;
    #pragma unroll
    for (int i = ty; i < 32; i += 8)
        tile[i][tx] = src[(size_t)(d0 + i) * NE + e0 + tx];
    __syncthreads();
    #pragma unroll
    for (int i = ty; i < 32; i += 8)
        dst[(size_t)(e0 + i) * Dm + d0 + tx] = tile[tx][i];
}

// ---------------------------------------------------------------- e2 norms (+ zero flag counter)
__global__ void k_e2(const float* __restrict__ emb, float* __restrict__ e2,
                     int* __restrict__ cnt){
    if (blockIdx.x == 0 && blockIdx.y == 0 && threadIdx.x == 0) *cnt = 0;
    const int n = blockIdx.y;
    const int e = (blockIdx.x << 8) + threadIdx.x;
    const float* p = emb + (size_t)n * Dm * NE + e;
    float s = 0.f;
    #pragma unroll 8
    for (int d = 0; d < Dm; ++d){ float v = p[(size_t)d * NE]; s = fmaf(v, v, s); }
    e2[n * NE + e] = s;
}

// ---------------------------------------------------------------- split embT into bf16 hi/lo
__global__ __launch_bounds__(256) void k_cvt(const float* __restrict__ embT,
                                             unsigned short* __restrict__ eh,
                                             unsigned short* __restrict__ el){
    const int i = ((blockIdx.x << 8) + threadIdx.x) << 2;
    const float4 v = *reinterpret_cast<const float4*>(&embT[i]);
    ushort4 h, l;
    bfsplit(v.x, h.x, l.x); bfsplit(v.y, h.y, l.y);
    bfsplit(v.z, h.z, l.z); bfsplit(v.w, h.w, l.w);
    *reinterpret_cast<ushort4*>(&eh[i]) = h;
    *reinterpret_cast<ushort4*>(&el[i]) = l;
}

// ---------------------------------------------------------------- prep banded conv weights
__global__ __launch_bounds__(256) void k_prep(
    const float* __restrict__ w0, const float* __restrict__ w1,
    const float* __restrict__ w2, const float* __restrict__ w3,
    unsigned short* __restrict__ bth, unsigned short* __restrict__ btl)
{
    const int dh = blockIdx.x;            // 0..6
    const int n  = blockIdx.y;            // 0..3
    const int kk = 2 * n + 1;
    if (dh >= kk) return;
    const float* wr[4] = { w0, w1, w2, w3 };
    const float* wp = wr[n] + dh * Dm;
    const int d = threadIdx.x;
    const size_t base = ((size_t)((n * 7 + dh) * 256 + d)) << 8;
    for (int mc = 0; mc < 256; mc += 4){
        ushort4 h, l;
        #pragma unroll
        for (int q = 0; q < 4; ++q){
            const int j = mc + q - d + 127;
            const float v = ((unsigned)j < 256u) ? wp[j] : 0.f;
            unsigned short hh, ll;
            bfsplit(v, hh, ll);
            (&h.x)[q] = hh; (&l.x)[q] = ll;
        }
        *reinterpret_cast<ushort4*>(&bth[base + mc]) = h;
        *reinterpret_cast<ushort4*>(&btl[base + mc]) = l;
    }
}

// ---------------------------------------------------------------- conv via split-bf16 MFMA
// Codebook-major. Emits f32 ic and pre-split bf16 hi/lo (ich/icl) for k_vq.
__global__ __launch_bounds__(256, 2) void k_conv(
    const float* __restrict__ x,
    const unsigned short* __restrict__ bth, const unsigned short* __restrict__ btl,
    const float* __restrict__ b0, const float* __restrict__ b1,
    const float* __restrict__ b2, const float* __restrict__ b3,
    float* __restrict__ ic,
    unsigned short* __restrict__ ich, unsigned short* __restrict__ icl)
{
    __shared__ alignas(16) unsigned short Ahs[70][264];
    __shared__ alignas(16) unsigned short Als[70][264];

    const int tid  = threadIdx.x;
    const int lane = tid & 63;
    const int w    = tid >> 6;
    const int tx   = lane & 15, tg = lane >> 4;
    const int bx   = blockIdx.x;
    const int n    = bx >> 8;             // codebook-major
    const int t0   = (bx & 255) << 6;
    const int bb   = t0 >> 11, s0 = t0 & (SEQ - 1);
    const int kk   = 2 * n + 1, pad = n;
    const int nrows = 64 + 2 * pad;

    for (int idx = tid; idx < (nrows << 6); idx += 256){
        const int r = idx >> 6, c4 = (idx & 63) << 2;
        const int s = s0 - pad + r;
        float4 v = make_float4(0.f, 0.f, 0.f, 0.f);
        if ((unsigned)s < (unsigned)SEQ)
            v = *reinterpret_cast<const float4*>(&x[(size_t)((bb << 11) + s) * Dm + c4]);
        ushort4 h, l;
        bfsplit(v.x, h.x, l.x); bfsplit(v.y, h.y, l.y);
        bfsplit(v.z, h.z, l.z); bfsplit(v.w, h.w, l.w);
        *reinterpret_cast<ushort4*>(&Ahs[r][c4]) = h;
        *reinterpret_cast<ushort4*>(&Als[r][c4]) = l;
    }
    __syncthreads();

    f32x4 acc[4][4];
    #pragma unroll
    for (int rb = 0; rb < 4; ++rb)
        #pragma unroll
        for (int cb = 0; cb < 4; ++cb)
            acc[rb][cb] = f32x4{0.f, 0.f, 0.f, 0.f};

    #pragma unroll 1
    for (int dh = 0; dh < kk; ++dh){
        #pragma unroll
        for (int ks = 0; ks < 8; ++ks){
            const int m0 = ks << 5;
            bf16x8 ah[4], al[4];
            #pragma unroll
            for (int rb = 0; rb < 4; ++rb){
                const int row = (rb << 4) + tx + dh;
                ah[rb] = *reinterpret_cast<const bf16x8*>(&Ahs[row][m0 + (tg << 3)]);
                al[rb] = *reinterpret_cast<const bf16x8*>(&Als[row][m0 + (tg << 3)]);
            }
            #pragma unroll
            for (int cb = 0; cb < 4; ++cb){
                const int d0 = (w << 6) + (cb << 4);
                if (m0 <= d0 + 143 && m0 >= d0 - 158){   // band-nonzero (wave-uniform)
                    const size_t gg = ((size_t)((n * 7 + dh) * 256 + d0 + tx) << 8) + m0 + (tg << 3);
                    const bf16x8 bh = *reinterpret_cast<const bf16x8*>(&bth[gg]);
                    const bf16x8 bl = *reinterpret_cast<const bf16x8*>(&btl[gg]);
                    #pragma unroll
                    for (int rb = 0; rb < 4; ++rb){
                        acc[rb][cb] = __builtin_amdgcn_mfma_f32_16x16x32_bf16(ah[rb], bh, acc[rb][cb], 0, 0, 0);
                        acc[rb][cb] = __builtin_amdgcn_mfma_f32_16x16x32_bf16(ah[rb], bl, acc[rb][cb], 0, 0, 0);
                        acc[rb][cb] = __builtin_amdgcn_mfma_f32_16x16x32_bf16(al[rb], bh, acc[rb][cb], 0, 0, 0);
                    }
                }
            }
        }
    }

    const float* bP[4] = { b0, b1, b2, b3 };
    const float bias = bP[n][0];
    #pragma unroll
    for (int rb = 0; rb < 4; ++rb)
        #pragma unroll
        for (int cb = 0; cb < 4; ++cb)
            #pragma unroll
            for (int r = 0; r < 4; ++r){
                const int trow = (rb << 4) + (tg << 2) + r;
                const int d    = (w << 6) + (cb << 4) + tx;
                const float v  = fmaxf(acc[rb][cb][r] + bias, 0.f);
                const size_t oidx = (size_t)(t0 + trow) * 1024 + (n << 8) + d;
                ic[oidx] = v;
                unsigned short hh, ll;
                bfsplit(v, hh, ll);
                ich[oidx] = hh; icl[oidx] = ll;
            }
}

// ---------------------------------------------------------------- VQ argmin v11: 32-row tiles, 3 blocks/CU
// LDS 33.8 KB + VGPR<=170 -> 12 waves/CU (3x TLP of v7). De-spilled per-cb loads.
__global__ __launch_bounds__(256, 3) void k_vq(
    const unsigned short* __restrict__ ich, const unsigned short* __restrict__ icl,
    const unsigned short* __restrict__ ebh, const unsigned short* __restrict__ ebl,
    const float* __restrict__ e2g, int* __restrict__ idx_ws, float* __restrict__ am,
    int* __restrict__ cnt, int2* __restrict__ flags)
{
    __shared__ alignas(16) unsigned short Ahs[32][264];
    __shared__ alignas(16) unsigned short Als[32][264];

    const int tid  = threadIdx.x;
    const int lane = tid & 63;
    const int w    = tid >> 6;
    const int tx   = lane & 15, tg = lane >> 4;
    const int bx   = blockIdx.x;
    const int n    = bx >> 9;             // codebook-major (512 t-tiles per n)
    const int t0   = (bx & 511) << 5;

    // ---- stage A from pre-split hi/lo (plain vector copies): 32 rows x 256
    #pragma unroll
    for (int i = 0; i < 4; ++i){
        const int idx = tid + (i << 8);          // 0..1023 over 32 rows x 32 chunks
        const int row = idx >> 5, ch = (idx & 31) << 3;
        const size_t g = (size_t)(t0 + row) * 1024 + (n << 8) + ch;
        *reinterpret_cast<us8*>(&Ahs[row][ch]) = *reinterpret_cast<const us8*>(&ich[g]);
        *reinterpret_cast<us8*>(&Als[row][ch]) = *reinterpret_cast<const us8*>(&icl[g]);
    }
    __syncthreads();

    float mn[8], mn2[8]; int mi[8];
    #pragma unroll
    for (int s = 0; s < 8; ++s){ mn[s] = 3.4e38f; mn2[s] = 3.4e38f; mi[s] = 0; }

    #pragma unroll 1
    for (int ec = 0; ec < 4; ++ec){
        f32x4 acc[2][4];
        #pragma unroll
        for (int rb = 0; rb < 2; ++rb)
            #pragma unroll
            for (int cb = 0; cb < 4; ++cb)
                acc[rb][cb] = f32x4{0.f, 0.f, 0.f, 0.f};

        #pragma unroll 2
        for (int ks = 0; ks < 8; ++ks){
            bf16x8 ah[2], al[2];
            #pragma unroll
            for (int rb = 0; rb < 2; ++rb){
                ah[rb] = *reinterpret_cast<const bf16x8*>(&Ahs[(rb << 4) + tx][(ks << 5) + (tg << 3)]);
                al[rb] = *reinterpret_cast<const bf16x8*>(&Als[(rb << 4) + tx][(ks << 5) + (tg << 3)]);
            }
            #pragma unroll
            for (int cb = 0; cb < 4; ++cb){
                const int e = (w << 8) + (ec << 6) + (cb << 4) + tx;
                const size_t gg = ((size_t)((n << 10) + e) << 8) + (ks << 5) + (tg << 3);
                const bf16x8 bh = *reinterpret_cast<const bf16x8*>(&ebh[gg]);
                const bf16x8 bl = *reinterpret_cast<const bf16x8*>(&ebl[gg]);
                #pragma unroll
                for (int rb = 0; rb < 2; ++rb){
                    acc[rb][cb] = __builtin_amdgcn_mfma_f32_16x16x32_bf16(ah[rb], bh, acc[rb][cb], 0, 0, 0);
                    acc[rb][cb] = __builtin_amdgcn_mfma_f32_16x16x32_bf16(ah[rb], bl, acc[rb][cb], 0, 0, 0);
                    acc[rb][cb] = __builtin_amdgcn_mfma_f32_16x16x32_bf16(al[rb], bh, acc[rb][cb], 0, 0, 0);
                }
            }
        }

        #pragma unroll
        for (int cb = 0; cb < 4; ++cb){
            const int e = (w << 8) + (ec << 6) + (cb << 4) + tx;
            const float ee = e2g[(n << 10) + e];
            #pragma unroll
            for (int rb = 0; rb < 2; ++rb)
                #pragma unroll
                for (int r = 0; r < 4; ++r){
                    const float v = fmaf(-2.f, acc[rb][cb][r], ee);
                    const int s = (rb << 2) + r;
                    if (v < mn[s]){ mn2[s] = mn[s]; mn[s] = v; mi[s] = e; }
                    else if (v < mn2[s]){ mn2[s] = v; }
                }
        }
    }

    // ---- reduce over 16 tx-lanes (disjoint e, same rows)
    #pragma unroll
    for (int sft = 1; sft < 16; sft <<= 1){
        #pragma unroll
        for (int s = 0; s < 8; ++s){
            const float om  = __shfl_xor(mn[s],  sft, 64);
            const float om2 = __shfl_xor(mn2[s], sft, 64);
            const int   oi  = __shfl_xor(mi[s],  sft, 64);
            if (om < mn[s] || (om == mn[s] && oi < mi[s])){
                mn2[s] = fminf(mn[s], om2);
                mn[s] = om; mi[s] = oi;
            } else {
                mn2[s] = fminf(mn2[s], om);
            }
        }
    }
    // ---- cross-wave merge (4 waves, disjoint e-strips) via LDS overlay
    __syncthreads();
    float* redMn  = reinterpret_cast<float*>(&Ahs[0][0]);   // [4][32]
    float* redMn2 = redMn + 128;
    int*   redMi  = reinterpret_cast<int*>(redMn + 256);
    if (tx == 0){
        #pragma unroll
        for (int rb = 0; rb < 2; ++rb)
            #pragma unroll
            for (int r = 0; r < 4; ++r){
                const int row = (rb << 4) + (tg << 2) + r;
                const int s = (rb << 2) + r;
                redMn [(w << 5) + row] = mn[s];
                redMn2[(w << 5) + row] = mn2[s];
                redMi [(w << 5) + row] = mi[s];
            }
    }
    __syncthreads();
    if (tid < 32){
        const int row = tid;
        float bmn = redMn[row], bmn2 = redMn2[row];
        int   bmi = redMi[row];
        #pragma unroll
        for (int wv = 1; wv < 4; ++wv){
            const float om  = redMn [(wv << 5) + row];
            const float om2 = redMn2[(wv << 5) + row];
            const int   oi  = redMi [(wv << 5) + row];
            if (om < bmn || (om == bmn && oi < bmi)){
                bmn2 = fminf(bmn, om2);
                bmn = om; bmi = oi;
            } else {
                bmn2 = fminf(bmn2, om);
            }
        }
        const int t = t0 + row;
        idx_ws[t * 4 + n] = bmi;
        am[(size_t)t * 4 + n] = (float)bmi;
        if (bmn2 - bmn < TAU){
            const int pos = atomicAdd(cnt, 1);
            if (pos < FLAGCAP) flags[pos] = make_int2(t, n);
        }
    }
}

// ---------------------------------------------------------------- f64 re-rank v3
// Thread-per-embedding distance pass (no shuffles in hot loop), LDS-staged conv.
__global__ __launch_bounds__(256) void k_fix(
    const float* __restrict__ x,
    const float* __restrict__ w0, const float* __restrict__ w1,
    const float* __restrict__ w2, const float* __restrict__ w3,
    const float* __restrict__ b0, const float* __restrict__ b1,
    const float* __restrict__ b2, const float* __restrict__ b3,
    const float* __restrict__ embT,
    const int* __restrict__ cnt, const int2* __restrict__ flags,
    int* __restrict__ idx_ws, float* __restrict__ am)
{
    __shared__ double xs[7][Dm];
    __shared__ double fl[Dm];
    __shared__ double rD[4];
    __shared__ int    rE[4];
    const int tid = threadIdx.x;
    const int lane = tid & 63, w = tid >> 6;
    const int total = (*cnt < FLAGCAP) ? *cnt : FLAGCAP;
    const float* wP[4] = { w0, w1, w2, w3 };
    const float* bP[4] = { b0, b1, b2, b3 };

    for (int item = blockIdx.x; item < total; item += gridDim.x){
        const int2 f = flags[item];
        const int t = f.x, n = f.y;
        const int bb = t >> 11, s = t & (SEQ - 1);
        const int k = 2 * n + 1, pad = n;
        for (int idx = tid; idx < (k << 8); idx += 256){
            const int r = idx >> 8, m = idx & 255;
            const int sr = s - pad + r;
            xs[r][m] = ((unsigned)sr < (unsigned)SEQ)
                       ? (double)x[(size_t)((bb << 11) + sr) * Dm + m] : 0.0;
        }
        __syncthreads();
        {
            const int d = tid;
            double a0 = (double)bP[n][0], a1 = 0.0;
            for (int dh = 0; dh < k; ++dh){
                const float* wr = wP[n] + dh * Dm;
                const int lo = (d - 127 < 0) ? 0 : d - 127;
                const int hi = (d + 129 > Dm) ? Dm : d + 129;
                int m = lo;
                for (; m + 1 < hi; m += 2){
                    a0 += xs[dh][m]     * (double)wr[m - d + 127];
                    a1 += xs[dh][m + 1] * (double)wr[m - d + 128];
                }
                if (m < hi) a0 += xs[dh][m] * (double)wr[m - d + 127];
            }
            const double acc = a0 + a1;
            fl[d] = (acc > 0.0) ? acc : 0.0;
        }
        __syncthreads();
        double bD = 1e300; int bE = 0;
        const float* ebase = embT + (size_t)n * NE * Dm;
        #pragma unroll 1
        for (int p = 0; p < 4; ++p){
            const int e = (p << 8) + tid;
            const float4* row = reinterpret_cast<const float4*>(&ebase[(size_t)e * Dm]);
            double d0 = 0.0, d1 = 0.0, s0 = 0.0, s1 = 0.0;
            for (int j = 0; j < 64; j += 2){
                const float4 va = row[j], vb = row[j + 1];
                const int m = j << 2;
                d0 += (double)va.x * fl[m]     + (double)va.y * fl[m + 1]
                    + (double)va.z * fl[m + 2] + (double)va.w * fl[m + 3];
                s0 += (double)va.x * (double)va.x + (double)va.y * (double)va.y
                    + (double)va.z * (double)va.z + (double)va.w * (double)va.w;
                d1 += (double)vb.x * fl[m + 4] + (double)vb.y * fl[m + 5]
                    + (double)vb.z * fl[m + 6] + (double)vb.w * fl[m + 7];
                s1 += (double)vb.x * (double)vb.x + (double)vb.y * (double)vb.y
                    + (double)vb.z * (double)vb.z + (double)vb.w * (double)vb.w;
            }
            const double dist = (s0 + s1) - 2.0 * (d0 + d1);
            if (dist < bD || (dist == bD && e < bE)){ bD = dist; bE = e; }
        }
        #pragma unroll
        for (int sft = 1; sft < 64; sft <<= 1){
            const double od = __shfl_xor(bD, sft, 64);
            const int    oe = __shfl_xor(bE, sft, 64);
            if (od < bD || (od == bD && oe < bE)){ bD = od; bE = oe; }
        }
        if (lane == 0){ rD[w] = bD; rE[w] = bE; }
        __syncthreads();
        if (tid == 0){
            #pragma unroll
            for (int wv = 1; wv < 4; ++wv)
                if (rD[wv] < rD[0] || (rD[wv] == rD[0] && rE[wv] < rE[0])){
                    rD[0] = rD[wv]; rE[0] = rE[wv];
                }
            idx_ws[t * 4 + n] = rE[0];
            am[(size_t)t * 4 + n] = (float)rE[0];
        }
        __syncthreads();
    }
}

// ---------------------------------------------------------------- gather + gate + z_q
__global__ __launch_bounds__(256) void k_final(
    const int* __restrict__ idx_ws, const float* __restrict__ embT,
    const float* __restrict__ gw, const float* __restrict__ gb,
    float* __restrict__ qc, float* __restrict__ zq)
{
    __shared__ float gws[4][Dm];
    const int tid = threadIdx.x;
    for (int i = tid; i < 4 * Dm; i += 256) gws[i >> 8][i & 255] = gw[i];
    __syncthreads();
    const int t = (blockIdx.x << 2) + (tid >> 6);
    const int lane = tid & 63, d0 = lane << 2;

    float q[4][4];
    #pragma unroll
    for (int n = 0; n < 4; ++n){
        const int e = idx_ws[t * 4 + n];
        const float4 v = *reinterpret_cast<const float4*>(
            &embT[((size_t)n * NE + e) * Dm + d0]);
        q[n][0] = v.x; q[n][1] = v.y; q[n][2] = v.z; q[n][3] = v.w;
        *reinterpret_cast<float4*>(&qc[(size_t)t * 1024 + n * Dm + d0]) = v;
    }
    float part[4];
    #pragma unroll
    for (int n = 0; n < 4; ++n){
        part[n] = q[0][0] * gws[n][d0]     + q[0][1] * gws[n][d0 + 1]
                + q[0][2] * gws[n][d0 + 2] + q[0][3] * gws[n][d0 + 3];
    }
    #pragma unroll
    for (int s = 1; s < 64; s <<= 1){
        #pragma unroll
        for (int n = 0; n < 4; ++n) part[n] += __shfl_xor(part[n], s, 64);
    }
    float lg[4];
    #pragma unroll
    for (int n = 0; n < 4; ++n) lg[n] = part[n] + gb[n];
    const float mx = fmaxf(fmaxf(lg[0], lg[1]), fmaxf(lg[2], lg[3]));
    float ex[4], ssum = 0.f;
    #pragma unroll
    for (int n = 0; n < 4; ++n){ ex[n] = expf(lg[n] - mx); ssum += ex[n]; }
    const float inv = 1.f / ssum;
    float z[4];
    #pragma unroll
    for (int dd = 0; dd < 4; ++dd)
        z[dd] = (ex[0] * q[0][dd] + ex[1] * q[1][dd] + ex[2] * q[2][dd] + ex[3] * q[3][dd]) * inv;
    *reinterpret_cast<float4*>(&zq[(size_t)t * Dm + d0]) =
        make_float4(z[0], z[1], z[2], z[3]);
}

// ---------------------------------------------------------------- launch
extern "C" void kernel_launch(void* const* d_in, const int* in_sizes, int n_in,
                              void* d_out, int out_size, void* d_ws, size_t ws_size,
                              hipStream_t stream)
{
    const float* x   = (const float*)d_in[0];
    const float* w0  = (const float*)d_in[1];
    const float* b0  = (const float*)d_in[2];
    const float* w1  = (const float*)d_in[3];
    const float* b1  = (const float*)d_in[4];
    const float* w2  = (const float*)d_in[5];
    const float* b2  = (const float*)d_in[6];
    const float* w3  = (const float*)d_in[7];
    const float* b3  = (const float*)d_in[8];
    const float* emb = (const float*)d_in[9];
    const float* gw  = (const float*)d_in[10];
    const float* gb  = (const float*)d_in[11];

    float* out = (float*)d_out;
    float* zq = out;                    //  4,194,304  (T x 256)
    float* am = out + 4194304;          //     65,536  (T x 4)
    float* ic = out + 4259840;          // 16,777,216  (T x 1024)
    float* qc = out + 21037056;         // 16,777,216  (T x 1024)
    // qc region doubles as pre-split scratch (fully overwritten by k_final)
    unsigned short* ich = (unsigned short*)qc;   // 16,777,216 ushorts
    unsigned short* icl = ich + 16777216;        // 16,777,216 ushorts

    float* ws    = (float*)d_ws;
    float* embT  = ws;                                      // [4][1024][256] f32
    float* e2    = ws + 1048576;                            // [4][1024]      f32
    int*   idxs  = (int*)(ws + 1052672);                    // [16384][4]     i32
    int*   cnt   = (int*)(ws + 1118208);                    // 1 i32
    int2*  flags = (int2*)(ws + 1118212);                   // FLAGCAP int2 -> ends 1380356
    unsigned short* ebh = (unsigned short*)(ws + 1380360);  // [4][1024][256] bf16 hi (524288 f)
    unsigned short* ebl = (unsigned short*)(ws + 1904648);  // [4][1024][256] bf16 lo (524288 f)
    unsigned short* bth = (unsigned short*)(ws + 2428936);  // [4][7][256][256] bf16 hi (917504 f)
    unsigned short* btl = (unsigned short*)(ws + 3346440);  // [4][7][256][256] bf16 lo (917504 f)

    hipLaunchKernelGGL(k_transpose, dim3(32, 8, 4), dim3(32, 8), 0, stream, emb, embT);
    hipLaunchKernelGGL(k_e2,        dim3(4, 4),     dim3(256),   0, stream, emb, e2, cnt);
    hipLaunchKernelGGL(k_cvt,       dim3(1024),     dim3(256),   0, stream, embT, ebh, ebl);
    hipLaunchKernelGGL(k_prep,      dim3(7, 4),     dim3(256),   0, stream,
                       w0, w1, w2, w3, bth, btl);
    hipLaunchKernelGGL(k_conv,      dim3(1024),     dim3(256),   0, stream,
                       x, bth, btl, b0, b1, b2, b3, ic, ich, icl);
    hipLaunchKernelGGL(k_vq,        dim3(2048),     dim3(256),   0, stream,
                       ich, icl, ebh, ebl, e2, idxs, am, cnt, flags);
    hipLaunchKernelGGL(k_fix,       dim3(2048),     dim3(256),   0, stream,
                       x, w0, w1, w2, w3, b0, b1, b2, b3, embT, cnt, flags, idxs, am);
    hipLaunchKernelGGL(k_final,     dim3(4096),     dim3(256),   0, stream,
                       idxs, embT, gw, gb, qc, zq);
}